// Round 8
// baseline (1034.447 us; speedup 1.0000x reference)
//
#include <hip/hip_runtime.h>
#include <hip/hip_bf16.h>

#define NVOX 200000
#define NK   125
#define GRID_LIN (128 * 128 * 128)

// workspace layout (bytes)
#define WT_OFF    0u                    // 125*64*64*2      = 1,024,000
#define STATS_OFF 1024000u              // 128*4            = 512
#define PFX_OFF   1024512u              // 2048*4           = 8,192
#define OLD_OFF   1032704u              // 200,000*4        = 800,000
#define FB_OFF    1832704u              // (N+1)*128        = 25,600,128  (128B aligned)
#define IDX_OFF   27432832u             // 2M*4             = 8,388,608   -> ends 35,821,440

#define F16N   (NVOX * 16)              // 3,200,000
#define WCONV_N (NK * 4096)             // 512,000
#define PREP_N (F16N + 16 + WCONV_N)    // 3,712,016

typedef short bf16x8 __attribute__((ext_vector_type(8)));
typedef float f32x4  __attribute__((ext_vector_type(4)));
typedef unsigned short u16x4 __attribute__((ext_vector_type(4)));
typedef unsigned int uint_as1 __attribute__((address_space(1)));
typedef unsigned int uint_as3 __attribute__((address_space(3)));

static __device__ __forceinline__ unsigned short f2bf(float f) {
    union { float f; unsigned int u; } v; v.f = f;
    unsigned int u = v.u;
    return (unsigned short)((u + 0x7FFFu + ((u >> 16) & 1u)) >> 16);   // RNE
}

// K1: scatter original voxel id into idx_map (pre-memset to -1)
__global__ __launch_bounds__(256) void scatter_kernel(const int* __restrict__ coords,
                                                      int* __restrict__ idx_map) {
    int p = blockIdx.x * 256 + threadIdx.x;
    if (p < NVOX) {
        int z = coords[p * 3 + 0], y = coords[p * 3 + 1], x = coords[p * 3 + 2];
        idx_map[(z << 14) | (y << 7) | x] = p;
    }
}

// K2: per-1024-cell occupancy count
__global__ __launch_bounds__(1024) void count_kernel(const int* __restrict__ idx_map,
                                                     int* __restrict__ pfx) {
    __shared__ int wsum[16];
    int i = blockIdx.x * 1024 + threadIdx.x;
    int bit = idx_map[i] >= 0 ? 1 : 0;
    unsigned long long m = __ballot(bit);
    int lane = threadIdx.x & 63, wave = threadIdx.x >> 6;
    if (lane == 0) wsum[wave] = __popcll(m);
    __syncthreads();
    if (threadIdx.x == 0) {
        int s = 0;
#pragma unroll
        for (int w = 0; w < 16; ++w) s += wsum[w];
        pfx[blockIdx.x] = s;
    }
}

// K3: exclusive scan of 2048 block counts, single block
__global__ __launch_bounds__(1024) void scan_kernel(int* __restrict__ pfx) {
    __shared__ int A[2048], B[2048];
    int t = threadIdx.x;
    A[t] = pfx[t]; A[t + 1024] = pfx[t + 1024];
    __syncthreads();
    int* src = A; int* dst = B;
    for (int off = 1; off < 2048; off <<= 1) {
        dst[t]        = src[t]        + (t >= off ? src[t - off] : 0);
        dst[t + 1024] = src[t + 1024] + src[t + 1024 - off];
        __syncthreads();
        int* tmp = src; src = dst; dst = tmp;
    }
    pfx[t]        = t ? src[t - 1] : 0;
    pfx[t + 1024] = src[t + 1023];
}

// K4: relabel cells in spatial order; idx_map[cell] <- new id; oldof[new] = old id
__global__ __launch_bounds__(1024) void relabel_kernel(const int* __restrict__ pfx,
                                                       int* __restrict__ idx_map,
                                                       int* __restrict__ oldof) {
    __shared__ int wsum[16];
    int i = blockIdx.x * 1024 + threadIdx.x;
    int old = idx_map[i];
    int bit = old >= 0 ? 1 : 0;
    unsigned long long m = __ballot(bit);
    int lane = threadIdx.x & 63, wave = threadIdx.x >> 6;
    int intra = __popcll(m & ((1ull << lane) - 1ull));
    if (lane == 0) wsum[wave] = __popcll(m);
    __syncthreads();
    int woff = 0;
    for (int w = 0; w < wave; ++w) woff += wsum[w];
    if (bit) {
        int nid = pfx[blockIdx.x] + woff + intra;
        idx_map[i] = nid;
        oldof[nid] = old;
    }
}

// K5: fused prep — feats permuted f32->bf16 (+zero row at index NVOX); W
// [125][ci][co] f32 -> lane-coalesced A-frag layout: ushort index within slice
// r = (a*2+half)*512 + lane*8 + e  holds W[co = a*16+(lane&15)]
//                                       [ci = half*32 + (lane>>4)*8 + e]
// so conv's af load = one contiguous 1KB global_load_dwordx4 per (a,half).
__global__ __launch_bounds__(256) void prep_kernel(const float* __restrict__ Wt,
                                                   const float* __restrict__ feats,
                                                   const int* __restrict__ oldof,
                                                   unsigned short* __restrict__ wt,
                                                   unsigned short* __restrict__ fb) {
    int i = blockIdx.x * 256 + threadIdx.x;
    if (i < F16N) {
        int p = i >> 4, c = i & 15;
        int old = oldof[p];
        f32x4 f = *(const f32x4*)(feats + (size_t)old * 64 + c * 4);
        u16x4 u;
        u[0] = f2bf(f[0]); u[1] = f2bf(f[1]); u[2] = f2bf(f[2]); u[3] = f2bf(f[3]);
        *(u16x4*)(fb + (size_t)i * 4) = u;
    } else if (i < F16N + 16) {
        *(u16x4*)(fb + (size_t)i * 4) = (u16x4)0;
    } else if (i < PREP_N) {
        int j = i - (F16N + 16);
        int k = j >> 12, r = j & 4095;
        int a2h = r >> 9;                 // a*2+half
        int ln  = (r >> 3) & 63;
        int e   = r & 7;
        int co  = (a2h >> 1) * 16 + (ln & 15);
        int ci  = (a2h & 1) * 32 + ((ln >> 4) << 3) + e;
        wt[(k << 12) + r] = f2bf(Wt[(k << 12) + (ci << 6) + co]);
    }
}

// Conv, round-6 LDS pipeline + OCCUPANCY fix. Round-6 counters: Occupancy
// 14.7% = 1.2 waves/SIMD — every stall exposed; all throughput pipes <15%.
// Fix: halve the per-wave tile (32 voxels, 2 MFMA t-tiles) -> 512-thread
// blocks of 8 waves, per-wave LDS 2 slots x 4KB = 64KB/block -> 2 blocks/CU
// = 16 waves/CU (3.4x round 6). launch_bounds(512,4) caps VGPR at 128.
// Pipeline per (dz,dy) group: stage kk=0,1 (4 gload_lds each, per-lane
// global src XOR-swizzled / linear LDS dst), probe next group's 5 cells
// BRANCH-FREE (clamped addr, always 5 loads -> deterministic vmcnt counts),
// then KK(0..4) with hand-counted vmcnt (9/17/12/12/8 = exact #ops-issued-
// after the stage each KK needs, INCLUDING the 8 af W-loads per KK;
// <= actual -> race-free), af (W) read from global/L1 (1KB coalesced,
// shared by both t-tiles), ~19%/tile zero-skip, one barrier/group to keep
// the 8 waves' W window L1-resident.
#define PROBEG(ge_, jj_) do {                                                \
    int dz_ = (ge_) / 5 - 2, dy_ = (ge_) % 5 - 2;                            \
    int nz_ = z + dz_, ny_ = y + dy_;                                        \
    bool rok_ = plive && ((unsigned)nz_ < 128u) && ((unsigned)ny_ < 128u);   \
    int base_ = (nz_ << 14) | (ny_ << 7);                                    \
    _Pragma("unroll")                                                        \
    for (int kk_ = 0; kk_ < 5; ++kk_) {                                      \
        int nx_ = x + kk_ - 2;                                               \
        bool ok_ = rok_ && ((unsigned)nx_ < 128u);                           \
        int addr_ = ok_ ? (base_ | nx_) : 0;                                 \
        int t_ = idx_map[addr_];                                             \
        jj_[kk_] = ok_ ? t_ : -1;                                            \
    }                                                                        \
} while (0)

#define STAGE(j5v, slot_) do {                                               \
    unsigned short* dst_ = &lds_b[wave][slot_][0] + lane * 8;                \
    _Pragma("unroll")                                                        \
    for (int i_ = 0; i_ < 4; ++i_) {                                         \
        int jv_ = __shfl((j5v), i_ * 8 + (lane >> 3), 64);                   \
        const char* src_ = fbp + ((size_t)(unsigned)jv_ << 7) + coff;        \
        __builtin_amdgcn_global_load_lds((const uint_as1*)(const void*)src_, \
            (uint_as3*)(void*)(dst_ + i_ * 512), 16, 0, 0);                  \
    }                                                                        \
} while (0)

#define KK(kk_, slot_, VM_) do {                                             \
    asm volatile("s_waitcnt vmcnt(" #VM_ ")" ::: "memory");                  \
    __builtin_amdgcn_sched_barrier(0);                                       \
    const char* bs_ = bwave + (slot_) * 4096;                                \
    bf16x8 b0A_ = *(const bf16x8*)(bs_ + sw0);                               \
    bf16x8 b1A_ = *(const bf16x8*)(bs_ + sw1);                               \
    bf16x8 b0B_ = *(const bf16x8*)(bs_ + 2048 + sw0);                        \
    bf16x8 b1B_ = *(const bf16x8*)(bs_ + 2048 + sw1);                        \
    __builtin_amdgcn_sched_barrier(0);                                       \
    const char* wk_ = wk + (size_t)(kk_) * 8192;                             \
    bf16x8 af0_[4], af1_[4];                                                 \
    _Pragma("unroll")                                                        \
    for (int a_ = 0; a_ < 4; ++a_) {                                         \
        af0_[a_] = *(const bf16x8*)(wk_ + a_ * 2048);                        \
        af1_[a_] = *(const bf16x8*)(wk_ + a_ * 2048 + 1024);                 \
    }                                                                        \
    __builtin_amdgcn_sched_barrier(0);                                       \
    if ((kk_) + 2 < 5) STAGE(j5[(kk_) + 2], (kk_) & 1);                      \
    __builtin_amdgcn_sched_barrier(0);                                       \
    __builtin_amdgcn_s_setprio(1);                                           \
    unsigned mA_ = (unsigned)(mk[kk_] & 0xFFFFull);                          \
    unsigned mB_ = (unsigned)((mk[kk_] >> 16) & 0xFFFFull);                  \
    if (mA_) {                                                               \
        _Pragma("unroll")                                                    \
        for (int a_ = 0; a_ < 4; ++a_) {                                     \
            accA[a_] = __builtin_amdgcn_mfma_f32_16x16x32_bf16(              \
                af0_[a_], b0A_, accA[a_], 0, 0, 0);                          \
            accA[a_] = __builtin_amdgcn_mfma_f32_16x16x32_bf16(              \
                af1_[a_], b1A_, accA[a_], 0, 0, 0);                          \
        }                                                                    \
    }                                                                        \
    if (mB_) {                                                               \
        _Pragma("unroll")                                                    \
        for (int a_ = 0; a_ < 4; ++a_) {                                     \
            accB[a_] = __builtin_amdgcn_mfma_f32_16x16x32_bf16(              \
                af0_[a_], b0B_, accB[a_], 0, 0, 0);                          \
            accB[a_] = __builtin_amdgcn_mfma_f32_16x16x32_bf16(              \
                af1_[a_], b1B_, accB[a_], 0, 0, 0);                          \
        }                                                                    \
    }                                                                        \
    __builtin_amdgcn_s_setprio(0);                                           \
} while (0)

__global__ __launch_bounds__(512, 4) void conv_kernel(
    const int* __restrict__ coords, const unsigned short* __restrict__ fb,
    const unsigned short* __restrict__ wt, const int* __restrict__ idx_map,
    const int* __restrict__ oldof,
    float* __restrict__ out, float* __restrict__ stats) {
    __shared__ unsigned short lds_b[8][2][2048];   // 64 KB: [wave][slot][4KB]

    const int vblk = (blockIdx.x & 7) * 98 + (blockIdx.x >> 3);
    const int vbase = vblk * 256;
    if (vbase >= NVOX) return;

    const int tid  = threadIdx.x;
    const int wave = tid >> 6;                    // 0..7
    const int lane = tid & 63;
    const int g    = lane >> 4;
    const int l15  = lane & 15;
    const int rot  = vblk % 25;                   // per-block k-phase offset

    // this wave owns 32 output voxels; lane probes voxel (lane&31)
    const int wvox = vbase + wave * 32;
    const int pv   = wvox + (lane & 31);
    const bool plive = pv < NVOX;

    int z = 0, y = 0, x = 0;
    if (plive) {
        int old = oldof[pv];
        z = coords[old * 3 + 0]; y = coords[old * 3 + 1]; x = coords[old * 3 + 2];
    }

    // lane constants
    const int coff = (((lane & 7) ^ ((lane >> 3) & 7)) << 4);  // stage src swizzle
    const int sw0  = ((g    ) ^ (l15 & 7)) << 4;               // read swizzle, half 0
    const int sw1  = ((4 + g) ^ (l15 & 7)) << 4;               // read swizzle, half 1
    const char* bwave = (const char*)&lds_b[wave][0][0] + (l15 << 7);
    const char* fbp = (const char*)fb;
    const char* wtp = (const char*)wt + lane * 16;

    f32x4 accA[4], accB[4];
#pragma unroll
    for (int a = 0; a < 4; ++a) { accA[a] = (f32x4)0.0f; accB[a] = (f32x4)0.0f; }

    // group-0 probe (loads retire before the loop: results consumed here)
    int j5[5];
    unsigned long long mk[5];
    {
        int jj[5];
        PROBEG(rot, jj);
#pragma unroll
        for (int kk = 0; kk < 5; ++kk) {
            mk[kk] = __ballot(jj[kk] >= 0);
            j5[kk] = jj[kk] < 0 ? NVOX : jj[kk];
        }
    }

#pragma unroll 1
    for (int grp = 0; grp < 25; ++grp) {
        int ge = grp + rot; if (ge >= 25) ge -= 25;
        const char* wk = wtp + (size_t)(ge * 5) * 8192;

        STAGE(j5[0], 0);                          // 4 VMEM
        STAGE(j5[1], 1);                          // 4 VMEM

        // probe next group ALWAYS (deterministic vmcnt counts; result unused
        // on grp==24): 5 VMEM, covered by >=2 KK bodies before forced wait
        int jn[5];
        int ge2 = ge + 1; if (ge2 >= 25) ge2 -= 25;
        PROBEG(ge2, jn);
        __builtin_amdgcn_sched_barrier(0);

        KK(0, 0, 9); KK(1, 1, 17); KK(2, 0, 12); KK(3, 1, 12); KK(4, 0, 8);

        if (grp < 24) {
#pragma unroll
            for (int kk = 0; kk < 5; ++kk) {
                mk[kk] = __ballot(jn[kk] >= 0);
                j5[kk] = jn[kk] < 0 ? NVOX : jn[kk];
            }
        }
        __syncthreads();   // keep 8 waves' W window L1-resident (no data dep)
    }

    // epilogue: scatter rows back to ORIGINAL voxel order (bias cancels under BN)
    {
        int vA = wvox + l15;
        if (vA < NVOX) {
            int o = oldof[vA];
#pragma unroll
            for (int a = 0; a < 4; ++a)
                *(f32x4*)(out + (size_t)o * 64 + a * 16 + g * 4) = accA[a];
        }
        int vB = wvox + 16 + l15;
        if (vB < NVOX) {
            int o = oldof[vB];
#pragma unroll
            for (int a = 0; a < 4; ++a)
                *(f32x4*)(out + (size_t)o * 64 + a * 16 + g * 4) = accB[a];
        }
    }

    // BN batch-stat partials over this wave's 32 voxels
    float s1[16], s2[16];
#pragma unroll
    for (int a = 0; a < 4; ++a)
#pragma unroll
        for (int r = 0; r < 4; ++r) {
            float xa = accA[a][r], xb = accB[a][r];
            s1[a * 4 + r] = xa + xb;
            s2[a * 4 + r] = xa * xa + xb * xb;
        }
#pragma unroll
    for (int m = 1; m < 16; m <<= 1) {
#pragma unroll
        for (int i = 0; i < 16; ++i) {
            s1[i] += __shfl_xor(s1[i], m, 64);
            s2[i] += __shfl_xor(s2[i], m, 64);
        }
    }
    if (l15 == 0) {
#pragma unroll
        for (int a = 0; a < 4; ++a)
#pragma unroll
            for (int r = 0; r < 4; ++r) {
                int co = a * 16 + g * 4 + r;
                atomicAdd(&stats[co],      s1[a * 4 + r]);
                atomicAdd(&stats[64 + co], s2[a * 4 + r]);
            }
    }
}

__global__ __launch_bounds__(256) void finalize_kernel(float* __restrict__ out,
                                                       const float* __restrict__ stats,
                                                       const float* __restrict__ gamma,
                                                       const float* __restrict__ beta) {
    int i = blockIdx.x * 256 + threadIdx.x;
    if (i >= NVOX * 16) return;
    int cg = (i & 15) * 4;
    f32x4 v = *(f32x4*)(out + (size_t)i * 4);
    f32x4 r;
#pragma unroll
    for (int c = 0; c < 4; ++c) {
        int co = cg + c;
        float mean = stats[co] * (1.0f / NVOX);
        float var  = stats[64 + co] * (1.0f / NVOX) - mean * mean;
        float sc   = rsqrtf(var + 1e-5f) * gamma[co];
        float sh   = beta[co] - mean * sc;
        float yv   = v[c] * sc + sh;
        r[c] = yv > 0.f ? yv : expm1f(yv);
    }
    *(f32x4*)(out + (size_t)i * 4) = r;
}

extern "C" void kernel_launch(void* const* d_in, const int* in_sizes, int n_in,
                              void* d_out, int out_size, void* d_ws, size_t ws_size,
                              hipStream_t stream) {
    const float* feats  = (const float*)d_in[0];
    const int*   coords = (const int*)d_in[1];
    const float* Wt     = (const float*)d_in[2];
    // d_in[3] = bias: unused — cancels exactly under training-mode BN
    const float* gamma  = (const float*)d_in[4];
    const float* beta   = (const float*)d_in[5];
    float* out = (float*)d_out;
    char*  ws  = (char*)d_ws;

    unsigned short* wt  = (unsigned short*)(ws + WT_OFF);
    float* stats        = (float*)(ws + STATS_OFF);
    int*   pfx          = (int*)(ws + PFX_OFF);
    int*   oldof        = (int*)(ws + OLD_OFF);
    unsigned short* fb  = (unsigned short*)(ws + FB_OFF);
    int*   idx_map      = (int*)(ws + IDX_OFF);

    hipMemsetAsync(idx_map, 0xFF, (size_t)GRID_LIN * 4, stream);  // -1
    hipMemsetAsync(stats, 0, 128 * 4, stream);

    scatter_kernel<<<(NVOX + 255) / 256, 256, 0, stream>>>(coords, idx_map);
    count_kernel<<<GRID_LIN / 1024, 1024, 0, stream>>>(idx_map, pfx);
    scan_kernel<<<1, 1024, 0, stream>>>(pfx);
    relabel_kernel<<<GRID_LIN / 1024, 1024, 0, stream>>>(pfx, idx_map, oldof);
    prep_kernel<<<(PREP_N + 255) / 256, 256, 0, stream>>>(Wt, feats, oldof, wt, fb);
    conv_kernel<<<784, 512, 0, stream>>>(coords, fb, wt, idx_map, oldof, out, stats);
    finalize_kernel<<<12500, 256, 0, stream>>>(out, stats, gamma, beta);
}

// Round 10
// 754.771 us; speedup vs baseline: 1.3705x; 1.3705x over previous
//
#include <hip/hip_runtime.h>
#include <hip/hip_bf16.h>

#define NVOX 200000
#define NK   125
#define GRID_LIN (128 * 128 * 128)

// workspace layout (bytes)
#define WT_OFF    0u                    // 125*64*64*2      = 1,024,000
#define STATS_OFF 1024000u              // 128*4            = 512
#define PFX_OFF   1024512u              // 2048*4           = 8,192
#define OLD_OFF   1032704u              // 200,000*4        = 800,000
#define FB_OFF    1832704u              // (N+1)*128        = 25,600,128  (128B aligned)
#define IDX_OFF   27432832u             // 2M*4             = 8,388,608   -> ends 35,821,440

#define F16N   (NVOX * 16)              // 3,200,000
#define WCONV_N (NK * 4096)             // 512,000
#define PREP_N (F16N + 16 + WCONV_N)    // 3,712,016

typedef short bf16x8 __attribute__((ext_vector_type(8)));
typedef float f32x4  __attribute__((ext_vector_type(4)));
typedef unsigned short u16x4 __attribute__((ext_vector_type(4)));
typedef unsigned int uint_as1 __attribute__((address_space(1)));
typedef unsigned int uint_as3 __attribute__((address_space(3)));

static __device__ __forceinline__ unsigned short f2bf(float f) {
    union { float f; unsigned int u; } v; v.f = f;
    unsigned int u = v.u;
    return (unsigned short)((u + 0x7FFFu + ((u >> 16) & 1u)) >> 16);   // RNE
}

// K1: scatter original voxel id into idx_map (pre-memset to -1)
__global__ __launch_bounds__(256) void scatter_kernel(const int* __restrict__ coords,
                                                      int* __restrict__ idx_map) {
    int p = blockIdx.x * 256 + threadIdx.x;
    if (p < NVOX) {
        int z = coords[p * 3 + 0], y = coords[p * 3 + 1], x = coords[p * 3 + 2];
        idx_map[(z << 14) | (y << 7) | x] = p;
    }
}

// K2: per-1024-cell occupancy count
__global__ __launch_bounds__(1024) void count_kernel(const int* __restrict__ idx_map,
                                                     int* __restrict__ pfx) {
    __shared__ int wsum[16];
    int i = blockIdx.x * 1024 + threadIdx.x;
    int bit = idx_map[i] >= 0 ? 1 : 0;
    unsigned long long m = __ballot(bit);
    int lane = threadIdx.x & 63, wave = threadIdx.x >> 6;
    if (lane == 0) wsum[wave] = __popcll(m);
    __syncthreads();
    if (threadIdx.x == 0) {
        int s = 0;
#pragma unroll
        for (int w = 0; w < 16; ++w) s += wsum[w];
        pfx[blockIdx.x] = s;
    }
}

// K3: exclusive scan of 2048 block counts, single block
__global__ __launch_bounds__(1024) void scan_kernel(int* __restrict__ pfx) {
    __shared__ int A[2048], B[2048];
    int t = threadIdx.x;
    A[t] = pfx[t]; A[t + 1024] = pfx[t + 1024];
    __syncthreads();
    int* src = A; int* dst = B;
    for (int off = 1; off < 2048; off <<= 1) {
        dst[t]        = src[t]        + (t >= off ? src[t - off] : 0);
        dst[t + 1024] = src[t + 1024] + src[t + 1024 - off];
        __syncthreads();
        int* tmp = src; src = dst; dst = tmp;
    }
    pfx[t]        = t ? src[t - 1] : 0;
    pfx[t + 1024] = src[t + 1023];
}

// K4: relabel cells in spatial order; idx_map[cell] <- new id; oldof[new] = old id
__global__ __launch_bounds__(1024) void relabel_kernel(const int* __restrict__ pfx,
                                                       int* __restrict__ idx_map,
                                                       int* __restrict__ oldof) {
    __shared__ int wsum[16];
    int i = blockIdx.x * 1024 + threadIdx.x;
    int old = idx_map[i];
    int bit = old >= 0 ? 1 : 0;
    unsigned long long m = __ballot(bit);
    int lane = threadIdx.x & 63, wave = threadIdx.x >> 6;
    int intra = __popcll(m & ((1ull << lane) - 1ull));
    if (lane == 0) wsum[wave] = __popcll(m);
    __syncthreads();
    int woff = 0;
    for (int w = 0; w < wave; ++w) woff += wsum[w];
    if (bit) {
        int nid = pfx[blockIdx.x] + woff + intra;
        idx_map[i] = nid;
        oldof[nid] = old;
    }
}

// K5: fused prep — feats permuted f32->bf16 (+zero row); W [125][ci][co] f32 ->
// XOR-swizzled [125][co][ci] bf16 image: 16B chunk c of row co lands at c^(co&7),
// so conv's afrag ds_read_b128 spreads 8 lanes/bank-quad (conflict-free).
__global__ __launch_bounds__(256) void prep_kernel(const float* __restrict__ Wt,
                                                   const float* __restrict__ feats,
                                                   const int* __restrict__ oldof,
                                                   unsigned short* __restrict__ wt,
                                                   unsigned short* __restrict__ fb) {
    int i = blockIdx.x * 256 + threadIdx.x;
    if (i < F16N) {
        int p = i >> 4, c = i & 15;
        int old = oldof[p];
        f32x4 f = *(const f32x4*)(feats + (size_t)old * 64 + c * 4);
        u16x4 u;
        u[0] = f2bf(f[0]); u[1] = f2bf(f[1]); u[2] = f2bf(f[2]); u[3] = f2bf(f[3]);
        *(u16x4*)(fb + (size_t)i * 4) = u;
    } else if (i < F16N + 16) {
        *(u16x4*)(fb + (size_t)i * 4) = (u16x4)0;
    } else if (i < PREP_N) {
        int j = i - (F16N + 16);
        int k = j >> 12, r = j & 4095;
        int co = r >> 6, ci = r & 63;
        int dst = (co << 6) | ((((ci >> 3) ^ (co & 7)) << 3) | (ci & 7));
        wt[(k << 12) + dst] = f2bf(Wt[(k << 12) + (ci << 6) + co]);
    }
}

// Conv: R2 structure (W-in-LDS, B direct global->VGPR, 4 t-tiles, 16 MFMA/kk/
// wave) + counted-vmcnt W pipeline. ROUND-9 BUG FIXED: block-shared W staging
// needs a CROSS-WAVE contract — vmcnt is per-wave, so each KK now does
// {own-stage-complete vmcnt} + {raw s_barrier} before reading the slot (m201
// pattern: counted wait + non-draining barrier; B-gathers and later stages
// stay in flight). 3 slots (24 KB) so the stage target is never the slot
// being read this KK or next KK: seq position p reads slot p%3, stages p+2
// into (p+2)%3 — that slot was consumed by ALL waves before the previous
// barrier. Hand vmcnt {15,23,18,18,18} = #own VMEM ops issued after the
// needed stage (valid at prologue AND steady state; over-wait only).
// LDS 24KB -> 3 blocks/CU (784-block grid = 3.06/CU), 12 waves/CU.
#define PROBEG(ge_, jj_) do {                                                \
    int dz_ = (ge_) / 5 - 2, dy_ = (ge_) % 5 - 2;                            \
    int nz_ = z + dz_, ny_ = y + dy_;                                        \
    bool rok_ = live && ((unsigned)nz_ < 128u) && ((unsigned)ny_ < 128u);    \
    int base_ = (nz_ << 14) | (ny_ << 7);                                    \
    _Pragma("unroll")                                                        \
    for (int kk_ = 0; kk_ < 5; ++kk_) {                                      \
        int nx_ = x + kk_ - 2;                                               \
        bool ok_ = rok_ && ((unsigned)nx_ < 128u);                           \
        int addr_ = ok_ ? (base_ | nx_) : 0;                                 \
        int t_ = idx_map[addr_];                                             \
        jj_[kk_] = ok_ ? t_ : -1;                                            \
    }                                                                        \
} while (0)

// stage one 8KB W slice into LDS slot sl_ (runtime): 256 threads x 2 x 16B
#define STAGEW(k_, sl_) do {                                                 \
    const unsigned short* s_ = wt + ((size_t)(unsigned)(k_) << 12) + tid * 8;\
    unsigned short* d_ = lds_w + (sl_) * 4096 + tid * 8;                     \
    __builtin_amdgcn_global_load_lds((const uint_as1*)(const void*)s_,       \
        (uint_as3*)(void*)d_, 16, 0, 0);                                     \
    __builtin_amdgcn_global_load_lds((const uint_as1*)(const void*)(s_+2048),\
        (uint_as3*)(void*)(d_ + 2048), 16, 0, 0);                            \
} while (0)

// KK body. Program order: 8 B-gathers | hand vmcnt (OWN stage of read slot
// retired) | s_barrier (ALL waves' stages retired) | 8 af ds_reads | stage
// seq+2 into (rs+2)%3 (slot consumed by all waves before previous barrier)
// | MFMAs (compiler emits counted vmcnt for B + lgkmcnt for af).
#define KK(kk_, VM_, stk_) do {                                              \
    bf16x8 b0_[4], b1_[4];                                                   \
    _Pragma("unroll")                                                        \
    for (int t_ = 0; t_ < 4; ++t_) {                                         \
        int jv_ = __shfl(j5[kk_], t_ * 16 + l15, 64);                        \
        const char* rp_ = fbp + ((size_t)(unsigned)jv_ << 7) + (g << 4);     \
        b0_[t_] = *(const bf16x8*)(rp_);                                     \
        b1_[t_] = *(const bf16x8*)(rp_ + 64);                                \
    }                                                                        \
    asm volatile("s_waitcnt vmcnt(" #VM_ ")" ::: "memory");                  \
    __builtin_amdgcn_s_barrier();                                            \
    __builtin_amdgcn_sched_barrier(0);                                       \
    int rs_ = s0 + (kk_); if (rs_ >= 3) rs_ -= 3; if (rs_ >= 3) rs_ -= 3;    \
    const char* wb_ = (const char*)(lds_w + rs_ * 4096);                     \
    bf16x8 af0_[4], af1_[4];                                                 \
    _Pragma("unroll")                                                        \
    for (int a_ = 0; a_ < 4; ++a_) {                                         \
        af0_[a_] = *(const bf16x8*)(wb_ + (((a_ * 16 + l15) << 7) | sw0));   \
        af1_[a_] = *(const bf16x8*)(wb_ + (((a_ * 16 + l15) << 7) | sw1));   \
    }                                                                        \
    __builtin_amdgcn_sched_barrier(0);                                       \
    int st_ = rs_ + 2; if (st_ >= 3) st_ -= 3;                               \
    STAGEW((stk_), st_);                                                     \
    __builtin_amdgcn_sched_barrier(0);                                       \
    __builtin_amdgcn_s_setprio(1);                                           \
    _Pragma("unroll")                                                        \
    for (int t_ = 0; t_ < 4; ++t_) {                                         \
        if ((unsigned)((mk[kk_] >> (t_ * 16)) & 0xFFFFull)) {                \
            _Pragma("unroll")                                                \
            for (int a_ = 0; a_ < 4; ++a_) {                                 \
                acc[a_][t_] = __builtin_amdgcn_mfma_f32_16x16x32_bf16(       \
                    af0_[a_], b0_[t_], acc[a_][t_], 0, 0, 0);                \
                acc[a_][t_] = __builtin_amdgcn_mfma_f32_16x16x32_bf16(       \
                    af1_[a_], b1_[t_], acc[a_][t_], 0, 0, 0);                \
            }                                                                \
        }                                                                    \
    }                                                                        \
    __builtin_amdgcn_s_setprio(0);                                           \
} while (0)

__global__ __launch_bounds__(256, 3) void conv_kernel(
    const int* __restrict__ coords, const unsigned short* __restrict__ fb,
    const unsigned short* __restrict__ wt, const int* __restrict__ idx_map,
    const int* __restrict__ oldof,
    float* __restrict__ out, float* __restrict__ stats) {
    __shared__ __align__(16) unsigned short lds_w[3 * 4096];   // 24 KB, 3 slots

    const int vblk = (blockIdx.x & 7) * 98 + (blockIdx.x >> 3);
    const int vbase = vblk * 256;
    if (vbase >= NVOX) return;

    const int tid  = threadIdx.x;
    const int wave = tid >> 6;
    const int lane = tid & 63;
    const int g    = lane >> 4;
    const int l15  = lane & 15;
    const int vox  = vbase + tid;
    const bool live = vox < NVOX;
    const int rot  = vblk % 25;                   // per-block k-phase offset

    int z = 0, y = 0, x = 0;
    if (live) {
        int old = oldof[vox];
        z = coords[old * 3 + 0]; y = coords[old * 3 + 1]; x = coords[old * 3 + 2];
    }
    const int sw0 = ((g    ) ^ (l15 & 7)) << 4;   // swizzled chunk offset, s=0
    const int sw1 = ((g + 4) ^ (l15 & 7)) << 4;   // s=1

    f32x4 acc[4][4];
#pragma unroll
    for (int a = 0; a < 4; ++a)
#pragma unroll
        for (int b = 0; b < 4; ++b) acc[a][b] = (f32x4)0.0f;

    const char* fbp = (const char*)fb;

    // group-0 probe + prologue W stages (seq 0,1 -> slots 0,1)
    int j5[5];
    unsigned long long mk[5];
    {
        int jj[5];
        PROBEG(rot, jj);
#pragma unroll
        for (int kk = 0; kk < 5; ++kk) {
            mk[kk] = __ballot(jj[kk] >= 0);
            j5[kk] = jj[kk] < 0 ? NVOX : jj[kk];
        }
    }
    STAGEW(rot * 5 + 0, 0);                       // 2 VMEM
    STAGEW(rot * 5 + 1, 1);                       // 2 VMEM

    int s0 = 0;                                   // (grp*5)%3, tracked incrementally
#pragma unroll 1
    for (int grp = 0; grp < 25; ++grp) {
        int ge = grp + rot; if (ge >= 25) ge -= 25;
        int ge2 = ge + 1;  if (ge2 >= 25) ge2 -= 25;
        const int kb = ge * 5;                    // this group's k base
        const int nb = ge2 * 5;                   // next group's k base

        // probe next group ALWAYS (5 VMEM, deterministic counts; unused grp 24)
        int jn[5];
        PROBEG(ge2, jn);
        __builtin_amdgcn_sched_barrier(0);

        KK(0, 15, kb + 2);
        KK(1, 23, kb + 3);
        KK(2, 18, kb + 4);
        KK(3, 18, nb + 0);
        KK(4, 18, nb + 1);

        if (grp < 24) {
#pragma unroll
            for (int kk = 0; kk < 5; ++kk) {
                mk[kk] = __ballot(jn[kk] >= 0);
                j5[kk] = jn[kk] < 0 ? NVOX : jn[kk];
            }
        }
        s0 += 2; if (s0 >= 3) s0 -= 3;
    }
    // drain overshoot stages (grp-24 staged next-group slices never read);
    // no gload_lds may be in flight at wave teardown
    asm volatile("s_waitcnt vmcnt(0)" ::: "memory");

    // epilogue: scatter rows back to ORIGINAL voxel order (bias cancels under BN)
#pragma unroll
    for (int b = 0; b < 4; ++b) {
        int v = vbase + wave * 64 + b * 16 + l15;
        if (v < NVOX) {
            int o = oldof[v];
#pragma unroll
            for (int a = 0; a < 4; ++a)
                *(f32x4*)(out + (size_t)o * 64 + a * 16 + g * 4) = acc[a][b];
        }
    }

    // BN batch-stat partials over this wave's 64 voxels
    float s1[16], s2[16];
#pragma unroll
    for (int a = 0; a < 4; ++a)
#pragma unroll
        for (int r = 0; r < 4; ++r) {
            float s = 0.f, q = 0.f;
#pragma unroll
            for (int b = 0; b < 4; ++b) { float xv = acc[a][b][r]; s += xv; q += xv * xv; }
            s1[a * 4 + r] = s; s2[a * 4 + r] = q;
        }
#pragma unroll
    for (int m = 1; m < 16; m <<= 1) {
#pragma unroll
        for (int i = 0; i < 16; ++i) {
            s1[i] += __shfl_xor(s1[i], m, 64);
            s2[i] += __shfl_xor(s2[i], m, 64);
        }
    }
    if (l15 == 0) {
#pragma unroll
        for (int a = 0; a < 4; ++a)
#pragma unroll
            for (int r = 0; r < 4; ++r) {
                int co = a * 16 + g * 4 + r;
                atomicAdd(&stats[co],      s1[a * 4 + r]);
                atomicAdd(&stats[64 + co], s2[a * 4 + r]);
            }
    }
}

__global__ __launch_bounds__(256) void finalize_kernel(float* __restrict__ out,
                                                       const float* __restrict__ stats,
                                                       const float* __restrict__ gamma,
                                                       const float* __restrict__ beta) {
    int i = blockIdx.x * 256 + threadIdx.x;
    if (i >= NVOX * 16) return;
    int cg = (i & 15) * 4;
    f32x4 v = *(f32x4*)(out + (size_t)i * 4);
    f32x4 r;
#pragma unroll
    for (int c = 0; c < 4; ++c) {
        int co = cg + c;
        float mean = stats[co] * (1.0f / NVOX);
        float var  = stats[64 + co] * (1.0f / NVOX) - mean * mean;
        float sc   = rsqrtf(var + 1e-5f) * gamma[co];
        float sh   = beta[co] - mean * sc;
        float yv   = v[c] * sc + sh;
        r[c] = yv > 0.f ? yv : expm1f(yv);
    }
    *(f32x4*)(out + (size_t)i * 4) = r;
}

extern "C" void kernel_launch(void* const* d_in, const int* in_sizes, int n_in,
                              void* d_out, int out_size, void* d_ws, size_t ws_size,
                              hipStream_t stream) {
    const float* feats  = (const float*)d_in[0];
    const int*   coords = (const int*)d_in[1];
    const float* Wt     = (const float*)d_in[2];
    // d_in[3] = bias: unused — cancels exactly under training-mode BN
    const float* gamma  = (const float*)d_in[4];
    const float* beta   = (const float*)d_in[5];
    float* out = (float*)d_out;
    char*  ws  = (char*)d_ws;

    unsigned short* wt  = (unsigned short*)(ws + WT_OFF);
    float* stats        = (float*)(ws + STATS_OFF);
    int*   pfx          = (int*)(ws + PFX_OFF);
    int*   oldof        = (int*)(ws + OLD_OFF);
    unsigned short* fb  = (unsigned short*)(ws + FB_OFF);
    int*   idx_map      = (int*)(ws + IDX_OFF);

    hipMemsetAsync(idx_map, 0xFF, (size_t)GRID_LIN * 4, stream);  // -1
    hipMemsetAsync(stats, 0, 128 * 4, stream);

    scatter_kernel<<<(NVOX + 255) / 256, 256, 0, stream>>>(coords, idx_map);
    count_kernel<<<GRID_LIN / 1024, 1024, 0, stream>>>(idx_map, pfx);
    scan_kernel<<<1, 1024, 0, stream>>>(pfx);
    relabel_kernel<<<GRID_LIN / 1024, 1024, 0, stream>>>(pfx, idx_map, oldof);
    prep_kernel<<<(PREP_N + 255) / 256, 256, 0, stream>>>(Wt, feats, oldof, wt, fb);
    conv_kernel<<<784, 256, 0, stream>>>(coords, fb, wt, idx_map, oldof, out, stats);
    finalize_kernel<<<12500, 256, 0, stream>>>(out, stats, gamma, beta);
}